// Round 6
// baseline (394.994 us; speedup 1.0000x reference)
//
#include <hip/hip_runtime.h>
#include <hip/hip_bf16.h>

#define Bsz 16
#define Nn  1024
#define Ff  256
#define TI  8
#define ALPHA 0.2f
#define NEG_BIG -9.0e15f

// ---- K0: w1 = W@a1 ; w2 = W@a2 --------------------------------------------
__global__ __launch_bounds__(256) void gat_prep(
    const float* __restrict__ W, const float* __restrict__ a,
    float* __restrict__ w1, float* __restrict__ w2)
{
    const int t = threadIdx.x, wv = t >> 6, ln = t & 63;
    __shared__ float a1s[Ff], a2s[Ff];
    a1s[t] = a[t];
    a2s[t] = a[Ff + t];
    __syncthreads();
    for (int f0 = 0; f0 < Ff; f0 += 4) {
        const int f = f0 + wv;
        float s1 = 0.f, s2 = 0.f;
        #pragma unroll
        for (int c = 0; c < 4; c++) {
            const int o = ln + 64 * c;
            const float w = W[(size_t)f * Ff + o];
            s1 += w * a1s[o];
            s2 += w * a2s[o];
        }
        #pragma unroll
        for (int off = 1; off < 64; off <<= 1) {
            s1 += __shfl_xor(s1, off, 64);
            s2 += __shfl_xor(s2, off, 64);
        }
        if (ln == 0) { w1[f] = s1; w2[f] = s2; }
    }
}

// ---- K1: f1 = h·w1 ; f2 = h·w2 (one wave per row) -------------------------
__global__ __launch_bounds__(256) void gat_f(
    const float* __restrict__ h,
    const float* __restrict__ w1, const float* __restrict__ w2,
    float* __restrict__ f1, float* __restrict__ f2)
{
    __shared__ float w1s[Ff], w2s[Ff];
    const int t = threadIdx.x, wv = t >> 6, ln = t & 63;
    w1s[t] = w1[t];
    w2s[t] = w2[t];
    __syncthreads();
    const int row = blockIdx.x * 4 + wv;
    float s1 = 0.f, s2 = 0.f;
    #pragma unroll
    for (int c = 0; c < 4; c++) {
        const int f = ln + 64 * c;
        const float hv = h[(size_t)row * Ff + f];
        s1 += hv * w1s[f];
        s2 += hv * w2s[f];
    }
    #pragma unroll
    for (int off = 1; off < 64; off <<= 1) {
        s1 += __shfl_xor(s1, off, 64);
        s2 += __shfl_xor(s2, off, 64);
    }
    if (ln == 0) { f1[row] = s1; f2[row] = s2; }
}

// ---- K2: softmax(mask(lrelu(f1_i+f2_j))) -> g=attn@h -> out=elu(g@W), f32 --
__global__ __launch_bounds__(256) void gat_attn(
    const float* __restrict__ h, const int* __restrict__ adj,
    const float* __restrict__ W,
    const float* __restrict__ f1, const float* __restrict__ f2,
    float* __restrict__ out)
{
    __shared__ float p[TI][Nn];    // 32 KiB softmax numerators
    __shared__ float fs2[Nn];      // 4 KiB
    __shared__ float gs[TI][Ff];   // 8 KiB  g = (attn @ h) rows
    __shared__ float dnm[TI];
    const int t = threadIdx.x, wv = t >> 6, ln = t & 63;
    const int b  = blockIdx.x / (Nn / TI);
    const int i0 = (blockIdx.x % (Nn / TI)) * TI;
    const int* adjb = adj + ((size_t)b * Nn + i0) * Nn;

    #pragma unroll
    for (int k = 0; k < 4; k++) fs2[t + 256 * k] = f2[b * Nn + t + 256 * k];
    __syncthreads();

    // Phase A: one wave per attention row
    for (int rr = 0; rr < TI; rr += 4) {
        const int r = rr + wv;
        const float fi = f1[b * Nn + i0 + r];
        float ev[16];
        float m = -INFINITY;
        #pragma unroll
        for (int c = 0; c < 16; c++) {
            const int j = ln + 64 * c;
            float e = fi + fs2[j];
            e = (e > 0.f) ? e : ALPHA * e;
            e = (adjb[(size_t)r * Nn + j] > 0) ? e : NEG_BIG;
            ev[c] = e;
            m = fmaxf(m, e);
        }
        #pragma unroll
        for (int off = 1; off < 64; off <<= 1) m = fmaxf(m, __shfl_xor(m, off, 64));
        float s = 0.f;
        #pragma unroll
        for (int c = 0; c < 16; c++) {
            const float pe = __expf(ev[c] - m);   // all-masked row -> uniform (matches ref)
            p[r][ln + 64 * c] = pe;
            s += pe;
        }
        #pragma unroll
        for (int off = 1; off < 64; off <<= 1) s += __shfl_xor(s, off, 64);
        if (ln == 0) dnm[r] = s;
    }
    __syncthreads();

    // Phase B: g[r][t] = (1/dnm[r]) * sum_j p[r][j] * h[b][j][t]
    float acc[TI];
    #pragma unroll
    for (int r = 0; r < TI; r++) acc[r] = 0.f;
    for (int j = 0; j < Nn; j++) {
        const float hv = h[((size_t)b * Nn + j) * Ff + t];
        #pragma unroll
        for (int r = 0; r < TI; r++) acc[r] += p[r][j] * hv;
    }
    #pragma unroll
    for (int r = 0; r < TI; r++) gs[r][t] = acc[r] / dnm[r];
    __syncthreads();

    // Phase C: out[r][t] = elu( sum_f gs[r][f] * W[f][t] ), f32 output
    float oc[TI];
    #pragma unroll
    for (int r = 0; r < TI; r++) oc[r] = 0.f;
    for (int f = 0; f < Ff; f++) {
        const float wv2 = W[(size_t)f * Ff + t];
        #pragma unroll
        for (int r = 0; r < TI; r++) oc[r] += gs[r][f] * wv2;
    }
    #pragma unroll
    for (int r = 0; r < TI; r++) {
        float v = oc[r];
        v = (v > 0.f) ? v : (__expf(v) - 1.0f);   // elu alpha=1
        out[((size_t)b * Nn + i0 + r) * Ff + t] = v;   // f32 — the round-5 fix
    }
}

extern "C" void kernel_launch(void* const* d_in, const int* in_sizes, int n_in,
                              void* d_out, int out_size, void* d_ws, size_t ws_size,
                              hipStream_t stream)
{
    const void* h   = d_in[0];
    const void* adj = d_in[1];
    const void* W   = d_in[2];
    const void* a   = d_in[3];
    // size-keyed remap (element counts are unique; robust to ordering)
    for (int i = 0; i < n_in; i++) {
        if      (in_sizes[i] == Bsz * Nn * Ff) h   = d_in[i];
        else if (in_sizes[i] == Bsz * Nn * Nn) adj = d_in[i];
        else if (in_sizes[i] == Ff * Ff)       W   = d_in[i];
        else if (in_sizes[i] == 2 * Ff)        a   = d_in[i];
    }
    float* out = (float*)d_out;

    // ws: 130 KiB total
    char*  wsb = (char*)d_ws;
    float* w1  = (float*)wsb;                      // 1 KiB
    float* w2  = w1 + Ff;                          // 1 KiB
    float* f1  = (float*)(wsb + 4096);             // 64 KiB
    float* f2  = f1 + Bsz * Nn;                    // 64 KiB

    gat_prep<<<1, 256, 0, stream>>>((const float*)W, (const float*)a, w1, w2);
    gat_f<<<(Bsz * Nn) / 4, 256, 0, stream>>>((const float*)h, w1, w2, f1, f2);
    gat_attn<<<(Bsz * Nn) / TI, 256, 0, stream>>>((const float*)h, (const int*)adj,
                                                  (const float*)W, f1, f2, out);
}

// Round 7
// 188.673 us; speedup vs baseline: 2.0935x; 2.0935x over previous
//
#include <hip/hip_runtime.h>
#include <hip/hip_bf16.h>

#define Bsz 16
#define Nn  1024
#define Ff  256
#define ALPHA 0.2f
#define NEG_BIG -9.0e15f

typedef __attribute__((ext_vector_type(8))) short short8;
typedef __attribute__((ext_vector_type(4))) float f32x4;

__device__ __forceinline__ unsigned short f2bf(float x) {
    union { __hip_bfloat16 b; unsigned short u; } cv;
    cv.b = __float2bfloat16(x);
    return cv.u;
}

// ---- K0: w1 = W@a1 ; w2 = W@a2 --------------------------------------------
__global__ __launch_bounds__(256) void gat_prep(
    const float* __restrict__ W, const float* __restrict__ a,
    float* __restrict__ w1, float* __restrict__ w2)
{
    const int t = threadIdx.x, wv = t >> 6, ln = t & 63;
    __shared__ float a1s[Ff], a2s[Ff];
    a1s[t] = a[t];
    a2s[t] = a[Ff + t];
    __syncthreads();
    for (int f0 = 0; f0 < Ff; f0 += 4) {
        const int f = f0 + wv;
        float s1 = 0.f, s2 = 0.f;
        #pragma unroll
        for (int c = 0; c < 4; c++) {
            const int o = ln + 64 * c;
            const float w = W[(size_t)f * Ff + o];
            s1 += w * a1s[o];
            s2 += w * a2s[o];
        }
        #pragma unroll
        for (int off = 1; off < 64; off <<= 1) {
            s1 += __shfl_xor(s1, off, 64);
            s2 += __shfl_xor(s2, off, 64);
        }
        if (ln == 0) { w1[f] = s1; w2[f] = s2; }
    }
}

// ---- K1: f1 = h·w1 ; f2 = h·w2 (one wave per row) -------------------------
__global__ __launch_bounds__(256) void gat_f(
    const float* __restrict__ h,
    const float* __restrict__ w1, const float* __restrict__ w2,
    float* __restrict__ f1, float* __restrict__ f2)
{
    __shared__ float w1s[Ff], w2s[Ff];
    const int t = threadIdx.x, wv = t >> 6, ln = t & 63;
    w1s[t] = w1[t];
    w2s[t] = w2[t];
    __syncthreads();
    const int row = blockIdx.x * 4 + wv;
    float s1 = 0.f, s2 = 0.f;
    #pragma unroll
    for (int c = 0; c < 4; c++) {
        const int f = ln + 64 * c;
        const float hv = h[(size_t)row * Ff + f];
        s1 += hv * w1s[f];
        s2 += hv * w2s[f];
    }
    #pragma unroll
    for (int off = 1; off < 64; off <<= 1) {
        s1 += __shfl_xor(s1, off, 64);
        s2 += __shfl_xor(s2, off, 64);
    }
    if (ln == 0) { f1[row] = s1; f2[row] = s2; }
}

// ---- K2: pack/transpose h and W to bf16, K-tiled for MFMA B-frags ---------
// blocks 0..511: (b,kt) of h -> hK[b][kt][n=256][kk=32] = h[b][kt*32+kk][n]
// blocks 512..519: ft of W   -> WK[ft][o=256][fk=32]    = W[ft*32+fk][o]
__global__ __launch_bounds__(256) void pack_transpose(
    const float* __restrict__ h, const float* __restrict__ W,
    unsigned short* __restrict__ hK, unsigned short* __restrict__ WK)
{
    __shared__ float tile[32][257];
    const int id = blockIdx.x, t = threadIdx.x;
    const float* src;
    unsigned short* dst;
    if (id < 512) {
        const int b = id >> 5, kt = id & 31;
        src = h + ((size_t)(b * Nn + kt * 32)) * Ff;
        dst = hK + ((size_t)(b * 32 + kt)) * 8192;
    } else {
        const int ft = id - 512;
        src = W + (size_t)ft * 32 * Ff;
        dst = WK + (size_t)ft * 8192;
    }
    #pragma unroll
    for (int rr = 0; rr < 8; rr++) {
        const int row = rr * 4 + (t >> 6);
        const int col = (t & 63) * 4;
        const float4 v = *(const float4*)&src[row * Ff + col];
        tile[row][col] = v.x; tile[row][col + 1] = v.y;
        tile[row][col + 2] = v.z; tile[row][col + 3] = v.w;
    }
    __syncthreads();
    unsigned* d32 = (unsigned*)dst;
    #pragma unroll
    for (int k = 0; k < 16; k++) {
        const int f = k * 256 + t;      // flat uint index; coalesced store
        const int o = f >> 4, q = f & 15;
        const unsigned lo = f2bf(tile[2 * q][o]);
        const unsigned hi = f2bf(tile[2 * q + 1][o]);
        d32[f] = lo | (hi << 16);
    }
}

// ---- K3: softmax (f32) -> G = P@h (MFMA) -> out = elu(G@W) (MFMA) ---------
#define TI 16
__global__ __launch_bounds__(256) void gat_attn(
    const int* __restrict__ adj,
    const float* __restrict__ f1, const float* __restrict__ f2,
    const unsigned short* __restrict__ hK, const unsigned short* __restrict__ WK,
    float* __restrict__ out)
{
    __shared__ unsigned short pbf[TI * 1032];  // P, bf16, row stride 1032 (pad)
    __shared__ unsigned short gbf[TI * 264];   // G, bf16, row stride 264 (pad)
    __shared__ float fs2[Nn];
    const int t = threadIdx.x, w = t >> 6, ln = t & 63;
    const int m = ln & 15, quad = ln >> 4;
    const int b  = blockIdx.x >> 6;
    const int i0 = (blockIdx.x & 63) * TI;

    #pragma unroll
    for (int k = 0; k < 4; k++) fs2[t + 256 * k] = f2[b * Nn + t + 256 * k];
    __syncthreads();

    // Phase A: wave w owns rows w*4..w*4+3; f32 softmax, normalized bf16 P
    for (int rr = 0; rr < 4; rr++) {
        const int r = w * 4 + rr;
        const float fi = f1[b * Nn + i0 + r];
        const int* adjr = adj + ((size_t)(b * Nn + i0 + r)) * Nn;
        float ev[16];
        float mx = -INFINITY;
        #pragma unroll
        for (int c = 0; c < 16; c++) {
            const int j = ln + 64 * c;
            float e = fi + fs2[j];
            e = (e > 0.f) ? e : ALPHA * e;
            e = (adjr[j] > 0) ? e : NEG_BIG;
            ev[c] = e;
            mx = fmaxf(mx, e);
        }
        #pragma unroll
        for (int off = 1; off < 64; off <<= 1) mx = fmaxf(mx, __shfl_xor(mx, off, 64));
        float s = 0.f;
        #pragma unroll
        for (int c = 0; c < 16; c++) {
            ev[c] = __expf(ev[c] - mx);   // all-masked row -> uniform (matches ref)
            s += ev[c];
        }
        #pragma unroll
        for (int off = 1; off < 64; off <<= 1) s += __shfl_xor(s, off, 64);
        const float rinv = 1.f / s;
        #pragma unroll
        for (int c = 0; c < 16; c++)
            pbf[r * 1032 + ln + 64 * c] = f2bf(ev[c] * rinv);
    }
    __syncthreads();

    // Phase B: G[16][256] = P[16][1024] @ h_b[1024][256], bf16 MFMA
    f32x4 acc[4] = {{0.f,0.f,0.f,0.f},{0.f,0.f,0.f,0.f},{0.f,0.f,0.f,0.f},{0.f,0.f,0.f,0.f}};
    const unsigned short* hKb = hK + (size_t)b * 32 * 8192;
    for (int kt = 0; kt < 32; kt++) {
        const short8 af = *(const short8*)&pbf[m * 1032 + kt * 32 + quad * 8];
        #pragma unroll
        for (int nt = 0; nt < 4; nt++) {
            const int n = w * 64 + nt * 16 + m;
            const short8 bf = *(const short8*)&hKb[(size_t)kt * 8192 + n * 32 + quad * 8];
            acc[nt] = __builtin_amdgcn_mfma_f32_16x16x32_bf16(af, bf, acc[nt], 0, 0, 0);
        }
    }
    // C-layout: D[row=quad*4+reg][col=lane&15] -> write G to LDS (A-layout rows)
    #pragma unroll
    for (int nt = 0; nt < 4; nt++)
        #pragma unroll
        for (int reg = 0; reg < 4; reg++)
            gbf[(quad * 4 + reg) * 264 + w * 64 + nt * 16 + m] = f2bf(acc[nt][reg]);
    __syncthreads();

    // Phase C: out = elu( G[16][256] @ W[256][256] ), bf16 MFMA
    f32x4 acc2[4] = {{0.f,0.f,0.f,0.f},{0.f,0.f,0.f,0.f},{0.f,0.f,0.f,0.f},{0.f,0.f,0.f,0.f}};
    for (int kt = 0; kt < 8; kt++) {
        const short8 af = *(const short8*)&gbf[m * 264 + kt * 32 + quad * 8];
        #pragma unroll
        for (int nt = 0; nt < 4; nt++) {
            const int n = w * 64 + nt * 16 + m;
            const short8 bf = *(const short8*)&WK[(size_t)kt * 8192 + n * 32 + quad * 8];
            acc2[nt] = __builtin_amdgcn_mfma_f32_16x16x32_bf16(af, bf, acc2[nt], 0, 0, 0);
        }
    }
    #pragma unroll
    for (int nt = 0; nt < 4; nt++) {
        #pragma unroll
        for (int reg = 0; reg < 4; reg++) {
            const int row = quad * 4 + reg;
            const int col = w * 64 + nt * 16 + m;
            float v = acc2[nt][reg];
            v = (v > 0.f) ? v : (__expf(v) - 1.0f);   // elu alpha=1
            out[((size_t)(b * Nn) + i0 + row) * Ff + col] = v;
        }
    }
}

extern "C" void kernel_launch(void* const* d_in, const int* in_sizes, int n_in,
                              void* d_out, int out_size, void* d_ws, size_t ws_size,
                              hipStream_t stream)
{
    const void* h   = d_in[0];
    const void* adj = d_in[1];
    const void* W   = d_in[2];
    const void* a   = d_in[3];
    for (int i = 0; i < n_in; i++) {
        if      (in_sizes[i] == Bsz * Nn * Ff) h   = d_in[i];
        else if (in_sizes[i] == Bsz * Nn * Nn) adj = d_in[i];
        else if (in_sizes[i] == Ff * Ff)       W   = d_in[i];
        else if (in_sizes[i] == 2 * Ff)        a   = d_in[i];
    }
    float* out = (float*)d_out;

    // ws layout (~8.45 MB): w1|w2|f1|f2|hK|WK  (all 16B-aligned offsets)
    char*  wsb = (char*)d_ws;
    float* w1  = (float*)wsb;                                   // 1 KiB
    float* w2  = w1 + Ff;                                       // 1 KiB
    float* f1  = (float*)(wsb + 4096);                          // 64 KiB
    float* f2  = f1 + Bsz * Nn;                                 // 64 KiB
    unsigned short* hK = (unsigned short*)(wsb + 4096 + 2 * 65536);       // 8 MiB
    unsigned short* WK = hK + (size_t)Bsz * 32 * 8192;                    // 128 KiB

    gat_prep<<<1, 256, 0, stream>>>((const float*)W, (const float*)a, w1, w2);
    pack_transpose<<<520, 256, 0, stream>>>((const float*)h, (const float*)W, hK, WK);
    gat_f<<<(Bsz * Nn) / 4, 256, 0, stream>>>((const float*)h, w1, w2, f1, f2);
    gat_attn<<<Bsz * (Nn / TI), 256, 0, stream>>>((const int*)adj, f1, f2, hK, WK, out);
}

// Round 8
// 159.154 us; speedup vs baseline: 2.4818x; 1.1855x over previous
//
#include <hip/hip_runtime.h>
#include <hip/hip_bf16.h>

#define Bsz 16
#define Nn  1024
#define Ff  256
#define ALPHA 0.2f
#define NEG_BIG -9.0e15f

typedef __attribute__((ext_vector_type(8))) short short8;
typedef __attribute__((ext_vector_type(4))) float f32x4;

__device__ __forceinline__ unsigned short f2bf(float x) {
    union { __hip_bfloat16 b; unsigned short u; } cv;
    cv.b = __float2bfloat16(x);
    return cv.u;
}

// ---- K0: w1 = W@a1 ; w2 = W@a2  (64 blocks, wave per output f) ------------
__global__ __launch_bounds__(256) void gat_prep(
    const float* __restrict__ W, const float* __restrict__ a,
    float* __restrict__ w1, float* __restrict__ w2)
{
    const int t = threadIdx.x, w = t >> 6, ln = t & 63;
    __shared__ float a1s[Ff], a2s[Ff];
    a1s[t] = a[t];
    a2s[t] = a[Ff + t];
    __syncthreads();
    const int f = blockIdx.x * 4 + w;
    float s1 = 0.f, s2 = 0.f;
    #pragma unroll
    for (int c = 0; c < 4; c++) {
        const int o = ln + 64 * c;
        const float wv = W[(size_t)f * Ff + o];
        s1 += wv * a1s[o];
        s2 += wv * a2s[o];
    }
    #pragma unroll
    for (int off = 1; off < 64; off <<= 1) {
        s1 += __shfl_xor(s1, off, 64);
        s2 += __shfl_xor(s2, off, 64);
    }
    if (ln == 0) { w1[f] = s1; w2[f] = s2; }
}

// ---- K1: pack/transpose h,W to bf16 K-tiles + fused f1/f2 -----------------
// blocks 0..511: (b,kt): hK[b][kt][n][kk] = h[b][kt*32+kk][n]; f1/f2 for 32 rows
// blocks 512..519: ft:    WK[ft][o][fk]   = W[ft*32+fk][o]
__global__ __launch_bounds__(256) void pack_f(
    const float* __restrict__ h, const float* __restrict__ W,
    const float* __restrict__ w1, const float* __restrict__ w2,
    unsigned short* __restrict__ hK, unsigned short* __restrict__ WK,
    float* __restrict__ f1, float* __restrict__ f2)
{
    __shared__ float tile[32][257];
    const int id = blockIdx.x, t = threadIdx.x, w = t >> 6, ln = t & 63;
    const bool isH = (id < 512);
    const float* src;
    unsigned short* dst;
    int grow0 = 0;
    if (isH) {
        const int b = id >> 5, kt = id & 31;
        grow0 = b * Nn + kt * 32;
        src = h + (size_t)grow0 * Ff;
        dst = hK + ((size_t)(b * 32 + kt)) * 8192;
    } else {
        const int ft = id - 512;
        src = W + (size_t)ft * 32 * Ff;
        dst = WK + (size_t)ft * 8192;
    }
    #pragma unroll
    for (int rr = 0; rr < 8; rr++) {
        const int row = rr * 4 + w;
        const int col = ln * 4;
        const float4 v = *(const float4*)&src[row * Ff + col];
        tile[row][col] = v.x; tile[row][col + 1] = v.y;
        tile[row][col + 2] = v.z; tile[row][col + 3] = v.w;
    }
    __syncthreads();

    // bf16 pack (coalesced dword stores)
    unsigned* d32 = (unsigned*)dst;
    #pragma unroll
    for (int k = 0; k < 16; k++) {
        const int fidx = k * 256 + t;
        const int o = fidx >> 4, q = fidx & 15;
        const unsigned lo = f2bf(tile[2 * q][o]);
        const unsigned hi = f2bf(tile[2 * q + 1][o]);
        d32[fidx] = lo | (hi << 16);
    }

    // fused f1/f2 from the LDS tile (h blocks only)
    if (isH) {
        float w1r[4], w2r[4];
        #pragma unroll
        for (int c = 0; c < 4; c++) {
            w1r[c] = w1[ln + 64 * c];
            w2r[c] = w2[ln + 64 * c];
        }
        #pragma unroll
        for (int rr = 0; rr < 8; rr++) {
            const int row = rr * 4 + w;
            float s1 = 0.f, s2 = 0.f;
            #pragma unroll
            for (int c = 0; c < 4; c++) {
                const float hv = tile[row][ln + 64 * c];
                s1 += hv * w1r[c];
                s2 += hv * w2r[c];
            }
            #pragma unroll
            for (int off = 1; off < 64; off <<= 1) {
                s1 += __shfl_xor(s1, off, 64);
                s2 += __shfl_xor(s2, off, 64);
            }
            if (ln == 0) { f1[grow0 + row] = s1; f2[grow0 + row] = s2; }
        }
    }
}

// ---- K2: softmax (f32) -> G = P@h (MFMA) -> out = elu(G@W) (MFMA) ---------
#define TI 16
__global__ __launch_bounds__(256, 4) void gat_attn(
    const int* __restrict__ adj,
    const float* __restrict__ f1, const float* __restrict__ f2,
    const unsigned short* __restrict__ hK, const unsigned short* __restrict__ WK,
    float* __restrict__ out)
{
    __shared__ unsigned short smem[TI * 1032];    // 33 KB: P (A/B), then G (C)
    const int t = threadIdx.x, w = t >> 6, ln = t & 63;
    const int m = ln & 15, quad = ln >> 4;
    // XCD swizzle: 64 blocks of a batch land on one XCD (L2-local hK)
    const int bid = blockIdx.x;
    const int b  = 2 * (bid & 7) + ((bid >> 3) & 1);
    const int i0 = (bid >> 4) * TI;

    // f2 for the whole batch row dimension, in registers
    float f2r[16];
    #pragma unroll
    for (int c = 0; c < 16; c++) f2r[c] = f2[b * Nn + ln + 64 * c];

    // Phase A: wave w owns rows w*4..+3, processed in pairs (loads overlapped)
    #pragma unroll
    for (int p = 0; p < 2; p++) {
        const int r0 = w * 4 + 2 * p, r1 = r0 + 1;
        const int gr0 = b * Nn + i0 + r0;
        const int* a0 = adj + (size_t)gr0 * Nn;
        const int* a1p = adj + (size_t)(gr0 + 1) * Nn;
        int av0[16], av1[16];
        #pragma unroll
        for (int c = 0; c < 16; c++) {
            av0[c] = a0[ln + 64 * c];
            av1[c] = a1p[ln + 64 * c];
        }
        const float fi0 = f1[gr0], fi1 = f1[gr0 + 1];
        float e0[16], e1[16];
        float mx0 = -INFINITY, mx1 = -INFINITY;
        #pragma unroll
        for (int c = 0; c < 16; c++) {
            float e = fi0 + f2r[c];
            e = (e > 0.f) ? e : ALPHA * e;
            e = (av0[c] > 0) ? e : NEG_BIG;
            e0[c] = e; mx0 = fmaxf(mx0, e);
            float g = fi1 + f2r[c];
            g = (g > 0.f) ? g : ALPHA * g;
            g = (av1[c] > 0) ? g : NEG_BIG;
            e1[c] = g; mx1 = fmaxf(mx1, g);
        }
        #pragma unroll
        for (int off = 1; off < 64; off <<= 1) {
            mx0 = fmaxf(mx0, __shfl_xor(mx0, off, 64));
            mx1 = fmaxf(mx1, __shfl_xor(mx1, off, 64));
        }
        float s0 = 0.f, s1 = 0.f;
        #pragma unroll
        for (int c = 0; c < 16; c++) {
            e0[c] = __expf(e0[c] - mx0); s0 += e0[c];   // all-masked row -> uniform
            e1[c] = __expf(e1[c] - mx1); s1 += e1[c];
        }
        #pragma unroll
        for (int off = 1; off < 64; off <<= 1) {
            s0 += __shfl_xor(s0, off, 64);
            s1 += __shfl_xor(s1, off, 64);
        }
        const float ri0 = 1.f / s0, ri1 = 1.f / s1;
        #pragma unroll
        for (int c = 0; c < 16; c++) {
            smem[r0 * 1032 + ln + 64 * c] = f2bf(e0[c] * ri0);
            smem[r1 * 1032 + ln + 64 * c] = f2bf(e1[c] * ri1);
        }
    }
    __syncthreads();

    // Phase B: G[16][256] = P @ h_b, bf16 MFMA (B-frags from L2-local hK)
    f32x4 acc[4] = {{0.f,0.f,0.f,0.f},{0.f,0.f,0.f,0.f},{0.f,0.f,0.f,0.f},{0.f,0.f,0.f,0.f}};
    const unsigned short* hKb = hK + (size_t)b * 32 * 8192;
    for (int kt = 0; kt < 32; kt++) {
        const short8 af = *(const short8*)&smem[m * 1032 + kt * 32 + quad * 8];
        #pragma unroll
        for (int nt = 0; nt < 4; nt++) {
            const int n = w * 64 + nt * 16 + m;
            const short8 bfv = *(const short8*)&hKb[(size_t)kt * 8192 + n * 32 + quad * 8];
            acc[nt] = __builtin_amdgcn_mfma_f32_16x16x32_bf16(af, bfv, acc[nt], 0, 0, 0);
        }
    }
    __syncthreads();   // P dead; reuse smem for G (stride 264)

    #pragma unroll
    for (int nt = 0; nt < 4; nt++)
        #pragma unroll
        for (int reg = 0; reg < 4; reg++)
            smem[(quad * 4 + reg) * 264 + w * 64 + nt * 16 + m] = f2bf(acc[nt][reg]);
    __syncthreads();

    // Phase C: out = elu( G @ W ), bf16 MFMA
    f32x4 acc2[4] = {{0.f,0.f,0.f,0.f},{0.f,0.f,0.f,0.f},{0.f,0.f,0.f,0.f},{0.f,0.f,0.f,0.f}};
    for (int kt = 0; kt < 8; kt++) {
        const short8 af = *(const short8*)&smem[m * 264 + kt * 32 + quad * 8];
        #pragma unroll
        for (int nt = 0; nt < 4; nt++) {
            const int n = w * 64 + nt * 16 + m;
            const short8 bfv = *(const short8*)&WK[(size_t)kt * 8192 + n * 32 + quad * 8];
            acc2[nt] = __builtin_amdgcn_mfma_f32_16x16x32_bf16(af, bfv, acc2[nt], 0, 0, 0);
        }
    }
    #pragma unroll
    for (int nt = 0; nt < 4; nt++) {
        #pragma unroll
        for (int reg = 0; reg < 4; reg++) {
            const int row = quad * 4 + reg;
            const int col = w * 64 + nt * 16 + m;
            float v = acc2[nt][reg];
            v = (v > 0.f) ? v : (__expf(v) - 1.0f);   // elu alpha=1
            out[((size_t)(b * Nn) + i0 + row) * Ff + col] = v;
        }
    }
}

extern "C" void kernel_launch(void* const* d_in, const int* in_sizes, int n_in,
                              void* d_out, int out_size, void* d_ws, size_t ws_size,
                              hipStream_t stream)
{
    const void* h   = d_in[0];
    const void* adj = d_in[1];
    const void* W   = d_in[2];
    const void* a   = d_in[3];
    for (int i = 0; i < n_in; i++) {
        if      (in_sizes[i] == Bsz * Nn * Ff) h   = d_in[i];
        else if (in_sizes[i] == Bsz * Nn * Nn) adj = d_in[i];
        else if (in_sizes[i] == Ff * Ff)       W   = d_in[i];
        else if (in_sizes[i] == 2 * Ff)        a   = d_in[i];
    }
    float* out = (float*)d_out;

    // ws layout (~8.45 MB): w1|w2|f1|f2|hK|WK (16B-aligned offsets)
    char*  wsb = (char*)d_ws;
    float* w1  = (float*)wsb;                                   // 1 KiB
    float* w2  = w1 + Ff;                                       // 1 KiB
    float* f1  = (float*)(wsb + 4096);                          // 64 KiB
    float* f2  = f1 + Bsz * Nn;                                 // 64 KiB
    unsigned short* hK = (unsigned short*)(wsb + 4096 + 2 * 65536);  // 8 MiB
    unsigned short* WK = hK + (size_t)Bsz * 32 * 8192;               // 128 KiB

    gat_prep<<<64, 256, 0, stream>>>((const float*)W, (const float*)a, w1, w2);
    pack_f<<<520, 256, 0, stream>>>((const float*)h, (const float*)W, w1, w2, hK, WK, f1, f2);
    gat_attn<<<Bsz * (Nn / TI), 256, 0, stream>>>((const int*)adj, f1, f2, hK, WK, out);
}

// Round 9
// 158.054 us; speedup vs baseline: 2.4991x; 1.0070x over previous
//
#include <hip/hip_runtime.h>
#include <hip/hip_bf16.h>

#define Bsz 16
#define Nn  1024
#define Ff  256
#define ALPHA 0.2f
#define NEG_BIG -9.0e15f

typedef __attribute__((ext_vector_type(8))) short short8;
typedef __attribute__((ext_vector_type(4))) float f32x4;
typedef __attribute__((ext_vector_type(4))) unsigned short ushort4_t;

__device__ __forceinline__ unsigned short f2bf(float x) {
    union { __hip_bfloat16 b; unsigned short u; } cv;
    cv.b = __float2bfloat16(x);
    return cv.u;
}

// ---- K0: w1 = W@a1 ; w2 = W@a2  (64 blocks, wave per output f) ------------
__global__ __launch_bounds__(256) void gat_prep(
    const float* __restrict__ W, const float* __restrict__ a,
    float* __restrict__ w1, float* __restrict__ w2)
{
    const int t = threadIdx.x, w = t >> 6, ln = t & 63;
    __shared__ float a1s[Ff], a2s[Ff];
    a1s[t] = a[t];
    a2s[t] = a[Ff + t];
    __syncthreads();
    const int f = blockIdx.x * 4 + w;
    float s1 = 0.f, s2 = 0.f;
    #pragma unroll
    for (int c = 0; c < 4; c++) {
        const int o = ln + 64 * c;
        const float wv = W[(size_t)f * Ff + o];
        s1 += wv * a1s[o];
        s2 += wv * a2s[o];
    }
    #pragma unroll
    for (int off = 1; off < 64; off <<= 1) {
        s1 += __shfl_xor(s1, off, 64);
        s2 += __shfl_xor(s2, off, 64);
    }
    if (ln == 0) { w1[f] = s1; w2[f] = s2; }
}

// ---- K1: pack/transpose h,W to bf16 K-tiles + fused f1/f2 -----------------
__global__ __launch_bounds__(256) void pack_f(
    const float* __restrict__ h, const float* __restrict__ W,
    const float* __restrict__ w1, const float* __restrict__ w2,
    unsigned short* __restrict__ hK, unsigned short* __restrict__ WK,
    float* __restrict__ f1, float* __restrict__ f2)
{
    __shared__ float tile[32][257];
    const int id = blockIdx.x, t = threadIdx.x, w = t >> 6, ln = t & 63;
    const bool isH = (id < 512);
    const float* src;
    unsigned short* dst;
    int grow0 = 0;
    if (isH) {
        const int b = id >> 5, kt = id & 31;
        grow0 = b * Nn + kt * 32;
        src = h + (size_t)grow0 * Ff;
        dst = hK + ((size_t)(b * 32 + kt)) * 8192;
    } else {
        const int ft = id - 512;
        src = W + (size_t)ft * 32 * Ff;
        dst = WK + (size_t)ft * 8192;
    }
    #pragma unroll
    for (int rr = 0; rr < 8; rr++) {
        const int row = rr * 4 + w;
        const int col = ln * 4;
        const float4 v = *(const float4*)&src[row * Ff + col];
        tile[row][col] = v.x; tile[row][col + 1] = v.y;
        tile[row][col + 2] = v.z; tile[row][col + 3] = v.w;
    }
    __syncthreads();

    unsigned* d32 = (unsigned*)dst;
    #pragma unroll
    for (int k = 0; k < 16; k++) {
        const int fidx = k * 256 + t;
        const int o = fidx >> 4, q = fidx & 15;
        const unsigned lo = f2bf(tile[2 * q][o]);
        const unsigned hi = f2bf(tile[2 * q + 1][o]);
        d32[fidx] = lo | (hi << 16);
    }

    if (isH) {
        float w1r[4], w2r[4];
        #pragma unroll
        for (int c = 0; c < 4; c++) {
            w1r[c] = w1[ln + 64 * c];
            w2r[c] = w2[ln + 64 * c];
        }
        #pragma unroll
        for (int rr = 0; rr < 8; rr++) {
            const int row = rr * 4 + w;
            float s1 = 0.f, s2 = 0.f;
            #pragma unroll
            for (int c = 0; c < 4; c++) {
                const float hv = tile[row][ln + 64 * c];
                s1 += hv * w1r[c];
                s2 += hv * w2r[c];
            }
            #pragma unroll
            for (int off = 1; off < 64; off <<= 1) {
                s1 += __shfl_xor(s1, off, 64);
                s2 += __shfl_xor(s2, off, 64);
            }
            if (ln == 0) { f1[grow0 + row] = s1; f2[grow0 + row] = s2; }
        }
    }
}

// ---- K2: softmax -> G = P@h (MFMA) -> out = elu(G@W) (MFMA), TI=32 --------
#define TI 32
__global__ __launch_bounds__(512, 4) void gat_attn(
    const int* __restrict__ adj,
    const float* __restrict__ f1, const float* __restrict__ f2,
    const unsigned short* __restrict__ hK, const unsigned short* __restrict__ WK,
    float* __restrict__ out)
{
    // 64 KB exactly: P (swizzled, stride 1024) in phases A/B; G (stride 264) in C
    __shared__ unsigned short pbf[TI * 1024];
    const int t = threadIdx.x, w = t >> 6, ln = t & 63;   // 8 waves
    const int m = ln & 15, quad = ln >> 4;
    const int bid = blockIdx.x;
    const int b  = 2 * (bid & 7) + ((bid >> 3) & 1);      // XCD-local batches
    const int i0 = (bid >> 4) * TI;

    float4 f2r[4];
    #pragma unroll
    for (int c = 0; c < 4; c++)
        f2r[c] = *(const float4*)&f2[b * Nn + 256 * c + 4 * ln];

    // ---- Phase A: wave w owns rows w*4..w*4+3 (2 pairs); int4 adj loads ----
    #pragma unroll
    for (int p = 0; p < 2; p++) {
        const int r0 = w * 4 + 2 * p, r1 = r0 + 1;
        const int gr = b * Nn + i0 + r0;
        const int* a0 = adj + (size_t)gr * Nn;
        const int* a1 = a0 + Nn;
        int4 av0[4], av1[4];
        #pragma unroll
        for (int c = 0; c < 4; c++) {
            av0[c] = *(const int4*)&a0[256 * c + 4 * ln];
            av1[c] = *(const int4*)&a1[256 * c + 4 * ln];
        }
        const float fi0 = f1[gr], fi1 = f1[gr + 1];
        float e0[16], e1[16];
        float mx0 = -INFINITY, mx1 = -INFINITY;
        #pragma unroll
        for (int c = 0; c < 4; c++) {
            const float4 fv = f2r[c];
            float x;
            x = fi0 + fv.x; x = x > 0.f ? x : ALPHA * x; x = av0[c].x > 0 ? x : NEG_BIG; e0[4*c+0] = x; mx0 = fmaxf(mx0, x);
            x = fi0 + fv.y; x = x > 0.f ? x : ALPHA * x; x = av0[c].y > 0 ? x : NEG_BIG; e0[4*c+1] = x; mx0 = fmaxf(mx0, x);
            x = fi0 + fv.z; x = x > 0.f ? x : ALPHA * x; x = av0[c].z > 0 ? x : NEG_BIG; e0[4*c+2] = x; mx0 = fmaxf(mx0, x);
            x = fi0 + fv.w; x = x > 0.f ? x : ALPHA * x; x = av0[c].w > 0 ? x : NEG_BIG; e0[4*c+3] = x; mx0 = fmaxf(mx0, x);
            x = fi1 + fv.x; x = x > 0.f ? x : ALPHA * x; x = av1[c].x > 0 ? x : NEG_BIG; e1[4*c+0] = x; mx1 = fmaxf(mx1, x);
            x = fi1 + fv.y; x = x > 0.f ? x : ALPHA * x; x = av1[c].y > 0 ? x : NEG_BIG; e1[4*c+1] = x; mx1 = fmaxf(mx1, x);
            x = fi1 + fv.z; x = x > 0.f ? x : ALPHA * x; x = av1[c].z > 0 ? x : NEG_BIG; e1[4*c+2] = x; mx1 = fmaxf(mx1, x);
            x = fi1 + fv.w; x = x > 0.f ? x : ALPHA * x; x = av1[c].w > 0 ? x : NEG_BIG; e1[4*c+3] = x; mx1 = fmaxf(mx1, x);
        }
        #pragma unroll
        for (int off = 1; off < 64; off <<= 1) {
            mx0 = fmaxf(mx0, __shfl_xor(mx0, off, 64));
            mx1 = fmaxf(mx1, __shfl_xor(mx1, off, 64));
        }
        float s0 = 0.f, s1 = 0.f;
        #pragma unroll
        for (int c = 0; c < 16; c++) {
            e0[c] = __expf(e0[c] - mx0); s0 += e0[c];   // all-masked row -> uniform
            e1[c] = __expf(e1[c] - mx1); s1 += e1[c];
        }
        #pragma unroll
        for (int off = 1; off < 64; off <<= 1) {
            s0 += __shfl_xor(s0, off, 64);
            s1 += __shfl_xor(s1, off, 64);
        }
        const float ri0 = 1.f / s0, ri1 = 1.f / s1;
        #pragma unroll
        for (int c = 0; c < 4; c++) {
            const int j = 256 * c + 4 * ln;
            ushort4_t v0 = { f2bf(e0[4*c] * ri0), f2bf(e0[4*c+1] * ri0),
                             f2bf(e0[4*c+2] * ri0), f2bf(e0[4*c+3] * ri0) };
            ushort4_t v1 = { f2bf(e1[4*c] * ri1), f2bf(e1[4*c+1] * ri1),
                             f2bf(e1[4*c+2] * ri1), f2bf(e1[4*c+3] * ri1) };
            *(ushort4_t*)&pbf[r0 * 1024 + (j ^ ((r0 & 7) << 3))] = v0;
            *(ushort4_t*)&pbf[r1 * 1024 + (j ^ ((r1 & 7) << 3))] = v1;
        }
    }
    __syncthreads();

    // ---- Phase B: G = P @ h_b, double-buffered bf16 MFMA ----
    const int mt = w & 1, n0 = (w >> 1) << 6;
    const unsigned short* hKb = hK + (size_t)b * 32 * 8192;
    const int arow = (mt * 16 + m) * 1024;
    const int asw  = (m & 7) << 3;
    f32x4 acc[4] = {{0.f,0.f,0.f,0.f},{0.f,0.f,0.f,0.f},{0.f,0.f,0.f,0.f},{0.f,0.f,0.f,0.f}};

    short8 afc = *(const short8*)&pbf[arow + ((quad * 8) ^ asw)];
    short8 bc[4];
    #pragma unroll
    for (int nt = 0; nt < 4; nt++)
        bc[nt] = *(const short8*)&hKb[(n0 + nt * 16 + m) * 32 + quad * 8];
    for (int kt = 0; kt < 31; kt++) {
        const short8 afn = *(const short8*)&pbf[arow + (((kt + 1) * 32 + quad * 8) ^ asw)];
        short8 bn[4];
        #pragma unroll
        for (int nt = 0; nt < 4; nt++)
            bn[nt] = *(const short8*)&hKb[(size_t)(kt + 1) * 8192 + (n0 + nt * 16 + m) * 32 + quad * 8];
        #pragma unroll
        for (int nt = 0; nt < 4; nt++)
            acc[nt] = __builtin_amdgcn_mfma_f32_16x16x32_bf16(afc, bc[nt], acc[nt], 0, 0, 0);
        afc = afn;
        #pragma unroll
        for (int nt = 0; nt < 4; nt++) bc[nt] = bn[nt];
    }
    #pragma unroll
    for (int nt = 0; nt < 4; nt++)
        acc[nt] = __builtin_amdgcn_mfma_f32_16x16x32_bf16(afc, bc[nt], acc[nt], 0, 0, 0);

    __syncthreads();   // P dead; reuse pbf for G (stride 264)
    #pragma unroll
    for (int nt = 0; nt < 4; nt++)
        #pragma unroll
        for (int reg = 0; reg < 4; reg++)
            pbf[(mt * 16 + quad * 4 + reg) * 264 + n0 + nt * 16 + m] = f2bf(acc[nt][reg]);
    __syncthreads();

    // ---- Phase C: out = elu( G @ W ) ----
    f32x4 acc2[4] = {{0.f,0.f,0.f,0.f},{0.f,0.f,0.f,0.f},{0.f,0.f,0.f,0.f},{0.f,0.f,0.f,0.f}};
    #pragma unroll
    for (int kt = 0; kt < 8; kt++) {
        const short8 af = *(const short8*)&pbf[(mt * 16 + m) * 264 + kt * 32 + quad * 8];
        #pragma unroll
        for (int nt = 0; nt < 4; nt++) {
            const short8 bv = *(const short8*)&WK[(size_t)kt * 8192 + (n0 + nt * 16 + m) * 32 + quad * 8];
            acc2[nt] = __builtin_amdgcn_mfma_f32_16x16x32_bf16(af, bv, acc2[nt], 0, 0, 0);
        }
    }
    #pragma unroll
    for (int nt = 0; nt < 4; nt++) {
        #pragma unroll
        for (int reg = 0; reg < 4; reg++) {
            const int row = mt * 16 + quad * 4 + reg;
            const int col = n0 + nt * 16 + m;
            float v = acc2[nt][reg];
            v = (v > 0.f) ? v : (__expf(v) - 1.0f);   // elu alpha=1
            out[((size_t)(b * Nn) + i0 + row) * Ff + col] = v;
        }
    }
}

extern "C" void kernel_launch(void* const* d_in, const int* in_sizes, int n_in,
                              void* d_out, int out_size, void* d_ws, size_t ws_size,
                              hipStream_t stream)
{
    const void* h   = d_in[0];
    const void* adj = d_in[1];
    const void* W   = d_in[2];
    const void* a   = d_in[3];
    for (int i = 0; i < n_in; i++) {
        if      (in_sizes[i] == Bsz * Nn * Ff) h   = d_in[i];
        else if (in_sizes[i] == Bsz * Nn * Nn) adj = d_in[i];
        else if (in_sizes[i] == Ff * Ff)       W   = d_in[i];
        else if (in_sizes[i] == 2 * Ff)        a   = d_in[i];
    }
    float* out = (float*)d_out;

    // ws layout (~8.45 MB): w1|w2|f1|f2|hK|WK (16B-aligned offsets)
    char*  wsb = (char*)d_ws;
    float* w1  = (float*)wsb;                                   // 1 KiB
    float* w2  = w1 + Ff;                                       // 1 KiB
    float* f1  = (float*)(wsb + 4096);                          // 64 KiB
    float* f2  = f1 + Bsz * Nn;                                 // 64 KiB
    unsigned short* hK = (unsigned short*)(wsb + 4096 + 2 * 65536);  // 8 MiB
    unsigned short* WK = hK + (size_t)Bsz * 32 * 8192;               // 128 KiB

    gat_prep<<<64, 256, 0, stream>>>((const float*)W, (const float*)a, w1, w2);
    pack_f<<<520, 256, 0, stream>>>((const float*)h, (const float*)W, w1, w2, hK, WK, f1, f2);
    gat_attn<<<Bsz * (Nn / TI), 512, 0, stream>>>((const int*)adj, f1, f2, hK, WK, out);
}

// Round 10
// 142.655 us; speedup vs baseline: 2.7689x; 1.1079x over previous
//
#include <hip/hip_runtime.h>
#include <hip/hip_bf16.h>

#define Bsz 16
#define Nn  1024
#define Ff  256
#define ALPHA 0.2f
#define NEG_BIG -9.0e15f

typedef __attribute__((ext_vector_type(8))) short short8;
typedef __attribute__((ext_vector_type(4))) float f32x4;
typedef __attribute__((ext_vector_type(4))) unsigned short ushort4_t;

__device__ __forceinline__ unsigned short f2bf(float x) {
    union { __hip_bfloat16 b; unsigned short u; } cv;
    cv.b = __float2bfloat16(x);
    return cv.u;
}

// ---- K0: w1 = W@a1 ; w2 = W@a2  (64 blocks, wave per output f) ------------
__global__ __launch_bounds__(256) void gat_prep(
    const float* __restrict__ W, const float* __restrict__ a,
    float* __restrict__ w1, float* __restrict__ w2)
{
    const int t = threadIdx.x, w = t >> 6, ln = t & 63;
    __shared__ float a1s[Ff], a2s[Ff];
    a1s[t] = a[t];
    a2s[t] = a[Ff + t];
    __syncthreads();
    const int f = blockIdx.x * 4 + w;
    float s1 = 0.f, s2 = 0.f;
    #pragma unroll
    for (int c = 0; c < 4; c++) {
        const int o = ln + 64 * c;
        const float wv = W[(size_t)f * Ff + o];
        s1 += wv * a1s[o];
        s2 += wv * a2s[o];
    }
    #pragma unroll
    for (int off = 1; off < 64; off <<= 1) {
        s1 += __shfl_xor(s1, off, 64);
        s2 += __shfl_xor(s2, off, 64);
    }
    if (ln == 0) { w1[f] = s1; w2[f] = s2; }
}

// ---- K1: pack/transpose h,W to bf16 K-tiles + fused f1/f2 -----------------
__global__ __launch_bounds__(256) void pack_f(
    const float* __restrict__ h, const float* __restrict__ W,
    const float* __restrict__ w1, const float* __restrict__ w2,
    unsigned short* __restrict__ hK, unsigned short* __restrict__ WK,
    float* __restrict__ f1, float* __restrict__ f2)
{
    __shared__ float tile[32][257];
    const int id = blockIdx.x, t = threadIdx.x, w = t >> 6, ln = t & 63;
    const bool isH = (id < 512);
    const float* src;
    unsigned short* dst;
    int grow0 = 0;
    if (isH) {
        const int b = id >> 5, kt = id & 31;
        grow0 = b * Nn + kt * 32;
        src = h + (size_t)grow0 * Ff;
        dst = hK + ((size_t)(b * 32 + kt)) * 8192;
    } else {
        const int ft = id - 512;
        src = W + (size_t)ft * 32 * Ff;
        dst = WK + (size_t)ft * 8192;
    }
    #pragma unroll
    for (int rr = 0; rr < 8; rr++) {
        const int row = rr * 4 + w;
        const int col = ln * 4;
        const float4 v = *(const float4*)&src[row * Ff + col];
        tile[row][col] = v.x; tile[row][col + 1] = v.y;
        tile[row][col + 2] = v.z; tile[row][col + 3] = v.w;
    }
    __syncthreads();

    unsigned* d32 = (unsigned*)dst;
    #pragma unroll
    for (int k = 0; k < 16; k++) {
        const int fidx = k * 256 + t;
        const int o = fidx >> 4, q = fidx & 15;
        const unsigned lo = f2bf(tile[2 * q][o]);
        const unsigned hi = f2bf(tile[2 * q + 1][o]);
        d32[fidx] = lo | (hi << 16);
    }

    if (isH) {
        float w1r[4], w2r[4];
        #pragma unroll
        for (int c = 0; c < 4; c++) {
            w1r[c] = w1[ln + 64 * c];
            w2r[c] = w2[ln + 64 * c];
        }
        #pragma unroll
        for (int rr = 0; rr < 8; rr++) {
            const int row = rr * 4 + w;
            float s1 = 0.f, s2 = 0.f;
            #pragma unroll
            for (int c = 0; c < 4; c++) {
                const float hv = tile[row][ln + 64 * c];
                s1 += hv * w1r[c];
                s2 += hv * w2r[c];
            }
            #pragma unroll
            for (int off = 1; off < 64; off <<= 1) {
                s1 += __shfl_xor(s1, off, 64);
                s2 += __shfl_xor(s2, off, 64);
            }
            if (ln == 0) { f1[grow0 + row] = s1; f2[grow0 + row] = s2; }
        }
    }
}

// ---- K2: softmax -> G = P@h (MFMA) -> out = elu(G@W) (MFMA), TI=32 --------
// Wave-to-tile mapping: each of 8 waves owns a distinct 32-col n-slice and
// BOTH 16-row m-halves -> every hK B-frag loaded exactly once per block.
#define TI 32
__global__ __launch_bounds__(512, 4) void gat_attn(
    const int* __restrict__ adj,
    const float* __restrict__ f1, const float* __restrict__ f2,
    const unsigned short* __restrict__ hK, const unsigned short* __restrict__ WK,
    float* __restrict__ out)
{
    // 64 KB exactly: P (swizzled, stride 1024) in phases A/B; G (stride 264) in C
    __shared__ unsigned short pbf[TI * 1024];
    const int t = threadIdx.x, w = t >> 6, ln = t & 63;   // 8 waves
    const int m = ln & 15, quad = ln >> 4;
    const int bid = blockIdx.x;
    const int b  = 2 * (bid & 7) + ((bid >> 3) & 1);      // XCD-local batches
    const int i0 = (bid >> 4) * TI;

    float4 f2r[4];
    #pragma unroll
    for (int c = 0; c < 4; c++)
        f2r[c] = *(const float4*)&f2[b * Nn + 256 * c + 4 * ln];

    // ---- Phase A: wave w owns rows w*4..w*4+3; pair-pipelined adj loads ----
    const int grb = b * Nn + i0 + w * 4;
    const int* aptr = adj + (size_t)grb * Nn;
    int4 av0[4], av1[4];
    #pragma unroll
    for (int c = 0; c < 4; c++) {
        av0[c] = *(const int4*)&aptr[c * 256 + 4 * ln];
        av1[c] = *(const int4*)&aptr[Nn + c * 256 + 4 * ln];
    }
    #pragma unroll
    for (int p = 0; p < 2; p++) {
        int4 nv0[4], nv1[4];
        if (p == 0) {
            #pragma unroll
            for (int c = 0; c < 4; c++) {
                nv0[c] = *(const int4*)&aptr[2 * Nn + c * 256 + 4 * ln];
                nv1[c] = *(const int4*)&aptr[3 * Nn + c * 256 + 4 * ln];
            }
        }
        const int r0 = w * 4 + 2 * p, r1 = r0 + 1;
        const float fi0 = f1[grb + 2 * p], fi1 = f1[grb + 2 * p + 1];
        float e0[16], e1[16];
        float mx0 = -INFINITY, mx1 = -INFINITY;
        #pragma unroll
        for (int c = 0; c < 4; c++) {
            const float4 fv = f2r[c];
            float x;
            x = fi0 + fv.x; x = x > 0.f ? x : ALPHA * x; x = av0[c].x > 0 ? x : NEG_BIG; e0[4*c+0] = x; mx0 = fmaxf(mx0, x);
            x = fi0 + fv.y; x = x > 0.f ? x : ALPHA * x; x = av0[c].y > 0 ? x : NEG_BIG; e0[4*c+1] = x; mx0 = fmaxf(mx0, x);
            x = fi0 + fv.z; x = x > 0.f ? x : ALPHA * x; x = av0[c].z > 0 ? x : NEG_BIG; e0[4*c+2] = x; mx0 = fmaxf(mx0, x);
            x = fi0 + fv.w; x = x > 0.f ? x : ALPHA * x; x = av0[c].w > 0 ? x : NEG_BIG; e0[4*c+3] = x; mx0 = fmaxf(mx0, x);
            x = fi1 + fv.x; x = x > 0.f ? x : ALPHA * x; x = av1[c].x > 0 ? x : NEG_BIG; e1[4*c+0] = x; mx1 = fmaxf(mx1, x);
            x = fi1 + fv.y; x = x > 0.f ? x : ALPHA * x; x = av1[c].y > 0 ? x : NEG_BIG; e1[4*c+1] = x; mx1 = fmaxf(mx1, x);
            x = fi1 + fv.z; x = x > 0.f ? x : ALPHA * x; x = av1[c].z > 0 ? x : NEG_BIG; e1[4*c+2] = x; mx1 = fmaxf(mx1, x);
            x = fi1 + fv.w; x = x > 0.f ? x : ALPHA * x; x = av1[c].w > 0 ? x : NEG_BIG; e1[4*c+3] = x; mx1 = fmaxf(mx1, x);
        }
        #pragma unroll
        for (int off = 1; off < 64; off <<= 1) {
            mx0 = fmaxf(mx0, __shfl_xor(mx0, off, 64));
            mx1 = fmaxf(mx1, __shfl_xor(mx1, off, 64));
        }
        float s0 = 0.f, s1 = 0.f;
        #pragma unroll
        for (int c = 0; c < 16; c++) {
            e0[c] = __expf(e0[c] - mx0); s0 += e0[c];   // all-masked row -> uniform
            e1[c] = __expf(e1[c] - mx1); s1 += e1[c];
        }
        #pragma unroll
        for (int off = 1; off < 64; off <<= 1) {
            s0 += __shfl_xor(s0, off, 64);
            s1 += __shfl_xor(s1, off, 64);
        }
        const float ri0 = 1.f / s0, ri1 = 1.f / s1;
        #pragma unroll
        for (int c = 0; c < 4; c++) {
            const int j = 256 * c + 4 * ln;
            ushort4_t v0 = { f2bf(e0[4*c] * ri0), f2bf(e0[4*c+1] * ri0),
                             f2bf(e0[4*c+2] * ri0), f2bf(e0[4*c+3] * ri0) };
            ushort4_t v1 = { f2bf(e1[4*c] * ri1), f2bf(e1[4*c+1] * ri1),
                             f2bf(e1[4*c+2] * ri1), f2bf(e1[4*c+3] * ri1) };
            *(ushort4_t*)&pbf[r0 * 1024 + (j ^ ((r0 & 7) << 3))] = v0;
            *(ushort4_t*)&pbf[r1 * 1024 + (j ^ ((r1 & 7) << 3))] = v1;
        }
        #pragma unroll
        for (int c = 0; c < 4; c++) { av0[c] = nv0[c]; av1[c] = nv1[c]; }
    }
    __syncthreads();

    // ---- Phase B: G = P @ h_b ; wave n-slice 32, both m-halves ----
    const int n0 = w * 32;
    const unsigned short* hKb = hK + (size_t)b * 32 * 8192;
    const int arow0 = m * 1024, arow1 = (16 + m) * 1024;
    const int asw = (m & 7) << 3;
    #define AF0(kt) (*(const short8*)&pbf[arow0 + ((((kt) * 32) + quad * 8) ^ asw)])
    #define AF1(kt) (*(const short8*)&pbf[arow1 + ((((kt) * 32) + quad * 8) ^ asw)])
    #define BF0(kt) (*(const short8*)&hKb[(size_t)(kt) * 8192 + (n0 + m) * 32 + quad * 8])
    #define BF1(kt) (*(const short8*)&hKb[(size_t)(kt) * 8192 + (n0 + 16 + m) * 32 + quad * 8])

    f32x4 acc00 = {0.f,0.f,0.f,0.f}, acc01 = acc00, acc10 = acc00, acc11 = acc00;
    short8 a0c = AF0(0), a1c = AF1(0);
    short8 b0c = BF0(0), b1c = BF1(0);
    short8 b0n = BF0(1), b1n = BF1(1);
    #pragma unroll
    for (int kt = 0; kt < 32; kt++) {
        short8 b0nn = b0c, b1nn = b1c, a0n = a0c, a1n = a1c;
        if (kt + 2 < 32) { b0nn = BF0(kt + 2); b1nn = BF1(kt + 2); }
        if (kt + 1 < 32) { a0n = AF0(kt + 1); a1n = AF1(kt + 1); }
        acc00 = __builtin_amdgcn_mfma_f32_16x16x32_bf16(a0c, b0c, acc00, 0, 0, 0);
        acc01 = __builtin_amdgcn_mfma_f32_16x16x32_bf16(a0c, b1c, acc01, 0, 0, 0);
        acc10 = __builtin_amdgcn_mfma_f32_16x16x32_bf16(a1c, b0c, acc10, 0, 0, 0);
        acc11 = __builtin_amdgcn_mfma_f32_16x16x32_bf16(a1c, b1c, acc11, 0, 0, 0);
        a0c = a0n; a1c = a1n; b0c = b0n; b1c = b1n; b0n = b0nn; b1n = b1nn;
    }

    __syncthreads();   // P dead; reuse pbf for G (stride 264)
    #pragma unroll
    for (int reg = 0; reg < 4; reg++) {
        pbf[(quad * 4 + reg) * 264 + n0 + m]           = f2bf(acc00[reg]);
        pbf[(quad * 4 + reg) * 264 + n0 + 16 + m]      = f2bf(acc01[reg]);
        pbf[(16 + quad * 4 + reg) * 264 + n0 + m]      = f2bf(acc10[reg]);
        pbf[(16 + quad * 4 + reg) * 264 + n0 + 16 + m] = f2bf(acc11[reg]);
    }
    __syncthreads();

    // ---- Phase C: out = elu( G @ W ) ; same wave mapping ----
    #define GA0(kt) (*(const short8*)&pbf[m * 264 + (kt) * 32 + quad * 8])
    #define GA1(kt) (*(const short8*)&pbf[(16 + m) * 264 + (kt) * 32 + quad * 8])
    #define WB0(kt) (*(const short8*)&WK[(size_t)(kt) * 8192 + (n0 + m) * 32 + quad * 8])
    #define WB1(kt) (*(const short8*)&WK[(size_t)(kt) * 8192 + (n0 + 16 + m) * 32 + quad * 8])

    f32x4 c00 = {0.f,0.f,0.f,0.f}, c01 = c00, c10 = c00, c11 = c00;
    short8 ga0 = GA0(0), ga1 = GA1(0);
    short8 wb0 = WB0(0), wb1 = WB1(0);
    #pragma unroll
    for (int kt = 0; kt < 8; kt++) {
        short8 ga0n = ga0, ga1n = ga1, wb0n = wb0, wb1n = wb1;
        if (kt + 1 < 8) { ga0n = GA0(kt+1); ga1n = GA1(kt+1); wb0n = WB0(kt+1); wb1n = WB1(kt+1); }
        c00 = __builtin_amdgcn_mfma_f32_16x16x32_bf16(ga0, wb0, c00, 0, 0, 0);
        c01 = __builtin_amdgcn_mfma_f32_16x16x32_bf16(ga0, wb1, c01, 0, 0, 0);
        c10 = __builtin_amdgcn_mfma_f32_16x16x32_bf16(ga1, wb0, c10, 0, 0, 0);
        c11 = __builtin_amdgcn_mfma_f32_16x16x32_bf16(ga1, wb1, c11, 0, 0, 0);
        ga0 = ga0n; ga1 = ga1n; wb0 = wb0n; wb1 = wb1n;
    }
    const size_t ob = (size_t)(b * Nn) + i0;
    #pragma unroll
    for (int reg = 0; reg < 4; reg++) {
        float v;
        v = c00[reg]; v = v > 0.f ? v : (__expf(v) - 1.f);
        out[(ob + quad * 4 + reg) * Ff + n0 + m] = v;
        v = c01[reg]; v = v > 0.f ? v : (__expf(v) - 1.f);
        out[(ob + quad * 4 + reg) * Ff + n0 + 16 + m] = v;
        v = c10[reg]; v = v > 0.f ? v : (__expf(v) - 1.f);
        out[(ob + 16 + quad * 4 + reg) * Ff + n0 + m] = v;
        v = c11[reg]; v = v > 0.f ? v : (__expf(v) - 1.f);
        out[(ob + 16 + quad * 4 + reg) * Ff + n0 + 16 + m] = v;
    }
}

extern "C" void kernel_launch(void* const* d_in, const int* in_sizes, int n_in,
                              void* d_out, int out_size, void* d_ws, size_t ws_size,
                              hipStream_t stream)
{
    const void* h   = d_in[0];
    const void* adj = d_in[1];
    const void* W   = d_in[2];
    const void* a   = d_in[3];
    for (int i = 0; i < n_in; i++) {
        if      (in_sizes[i] == Bsz * Nn * Ff) h   = d_in[i];
        else if (in_sizes[i] == Bsz * Nn * Nn) adj = d_in[i];
        else if (in_sizes[i] == Ff * Ff)       W   = d_in[i];
        else if (in_sizes[i] == 2 * Ff)        a   = d_in[i];
    }
    float* out = (float*)d_out;

    char*  wsb = (char*)d_ws;
    float* w1  = (float*)wsb;                                   // 1 KiB
    float* w2  = w1 + Ff;                                       // 1 KiB
    float* f1  = (float*)(wsb + 4096);                          // 64 KiB
    float* f2  = f1 + Bsz * Nn;                                 // 64 KiB
    unsigned short* hK = (unsigned short*)(wsb + 4096 + 2 * 65536);  // 8 MiB
    unsigned short* WK = hK + (size_t)Bsz * 32 * 8192;               // 128 KiB

    gat_prep<<<64, 256, 0, stream>>>((const float*)W, (const float*)a, w1, w2);
    pack_f<<<520, 256, 0, stream>>>((const float*)h, (const float*)W, w1, w2, hK, WK, f1, f2);
    gat_attn<<<Bsz * (Nn / TI), 512, 0, stream>>>((const int*)adj, f1, f2, hK, WK, out);
}